// Round 12
// baseline (162.629 us; speedup 1.0000x reference)
//
#include <hip/hip_runtime.h>
#include <stdint.h>
#include <type_traits>

typedef unsigned short u16;
typedef unsigned int u32;
typedef __attribute__((ext_vector_type(8))) short frag8;   // 8 bf16 (4 VGPRs)
typedef __attribute__((ext_vector_type(4))) float fx4;     // 4 fp32 acc
typedef __attribute__((ext_vector_type(16))) float fx16;   // 16 fp32 acc (32x32)

#define MFMA(a, b, c) __builtin_amdgcn_mfma_f32_16x16x32_bf16((a), (b), (c), 0, 0, 0)
#define MFMA32(a, b, c) __builtin_amdgcn_mfma_f32_32x32x16_bf16((a), (b), (c), 0, 0, 0)

__device__ __forceinline__ void gload16(const void* g, void* l) {
  __builtin_amdgcn_global_load_lds((const __attribute__((address_space(1))) void*)g,
                                   (__attribute__((address_space(3))) void*)l, 16, 0, 0);
}

__device__ __forceinline__ u16 f2bf(float f) {
  union { float f; unsigned int u; } c; c.f = f;
  unsigned int r = c.u + 0x7FFFu + ((c.u >> 16) & 1u);  // RNE
  return (u16)(r >> 16);
}

__device__ __forceinline__ u32 cvtpk(float lo, float hi) {
  u32 r;
  asm("v_cvt_pk_bf16_f32 %0, %1, %2" : "=v"(r) : "v"(lo), "v"(hi));
  return r;
}

__device__ __forceinline__ float fmax3(float a, float b, float c) {
  return fmaxf(fmaxf(a, b), c);  // clang fuses to v_max3_f32
}

// ---------------- conversions ----------------

__global__ __launch_bounds__(256) void cvt_x(const float* __restrict__ x, u16* __restrict__ xb) {
  const int n4 = (8192 * 1024) / 4;
  for (int i = blockIdx.x * 256 + threadIdx.x; i < n4; i += 2048 * 256) {
    float4 v = ((const float4*)x)[i];
    ushort4 o;
    o.x = f2bf(v.x); o.y = f2bf(v.y); o.z = f2bf(v.z); o.w = f2bf(v.w);
    ((ushort4*)xb)[i] = o;
  }
}

// Wq/Wk/Wv [H][C][D] -> Wt [(type*16+h)*64+d][c]  (N=3072 rows, K=1024)
__global__ __launch_bounds__(256) void cvt_wqkv(const float* __restrict__ Wq,
                                                const float* __restrict__ Wk,
                                                const float* __restrict__ Wv,
                                                u16* __restrict__ Wt) {
  __shared__ u16 Tls[64][72];  // +pad
  int hh = blockIdx.x;            // 0..47
  int c0 = blockIdx.y * 64;
  int type = hh >> 4, h = hh & 15;
  const float* Wsrc = (type == 0 ? Wq : (type == 1 ? Wk : Wv)) + (size_t)h * 1024 * 64;
  int t = threadIdx.x;
  int cr = t >> 4, q4 = (t & 15) * 4;
  for (int i = 0; i < 4; ++i) {
    int c = cr + i * 16;
    float4 v = *(const float4*)(Wsrc + (size_t)(c0 + c) * 64 + q4);
    Tls[q4 + 0][c] = f2bf(v.x);
    Tls[q4 + 1][c] = f2bf(v.y);
    Tls[q4 + 2][c] = f2bf(v.z);
    Tls[q4 + 3][c] = f2bf(v.w);
  }
  __syncthreads();
  for (int i = 0; i < 4; ++i) {
    int d = cr + i * 16;
    ushort4 o;
    o.x = Tls[d][q4 + 0]; o.y = Tls[d][q4 + 1]; o.z = Tls[d][q4 + 2]; o.w = Tls[d][q4 + 3];
    *(ushort4*)(Wt + ((size_t)hh * 64 + d) * 1024 + c0 + q4) = o;
  }
}

__global__ __launch_bounds__(256) void cvt_wp(const float* __restrict__ Wp, u16* __restrict__ wb) {
  const int n4 = (1024 * 1024) / 4;
  for (int i = blockIdx.x * 256 + threadIdx.x; i < n4; i += 1024 * 256) {
    float4 v = ((const float4*)Wp)[i];
    ushort4 o;
    o.x = f2bf(v.x); o.y = f2bf(v.y); o.z = f2bf(v.z); o.w = f2bf(v.w);
    ((ushort4*)wb)[i] = o;
  }
}

// V [bh][2048][64] -> VT [bh][64][2048]
__global__ __launch_bounds__(256) void transpose_v(const u16* __restrict__ Vb, u16* __restrict__ VTg) {
  __shared__ u16 T[64 * 64];  // chunk-XOR swizzled rows of 128B
  int bh = blockIdx.x, t0 = blockIdx.y * 64;
  const u16* src = Vb + ((size_t)bh * 2048 + t0) * 64;
  int tid = threadIdx.x;
  int tl = tid >> 2, c16 = (tid & 3) * 16;
  int swzw = (tl & 7) << 4;
  frag8 a = *(const frag8*)(src + (size_t)tl * 64 + c16);
  frag8 b = *(const frag8*)(src + (size_t)tl * 64 + c16 + 8);
  *(frag8*)((char*)T + tl * 128 + ((c16 * 2) ^ swzw)) = a;
  *(frag8*)((char*)T + tl * 128 + ((c16 * 2 + 16) ^ swzw)) = b;
  __syncthreads();
  int d_ = tid & 63;
#pragma unroll
  for (int k = 0; k < 2; ++k) {
    int c_ = (tid >> 6) + 4 * k;
    frag8 o;
#pragma unroll
    for (int j = 0; j < 8; ++j) {
      int t = c_ * 8 + j;
      o[j] = *(const u16*)((const char*)T + t * 128 + ((2 * d_) ^ ((t & 7) << 4)));
    }
    *(frag8*)(VTg + ((size_t)bh * 64 + d_) * 2048 + t0 + c_ * 8) = o;
  }
}

// ---------------- GEMM: BM=256, BN=192/128, BK=64, 512 thr ----------------
// ONE barrier per K-tile; A double-buffered, B triple-buffered; counted vmcnt(NB).
// READ PIPELINE: A-frags held in regs for the whole tile; B read in ni-pairs,
// pair p+1's ds_reads issued between pair p's MFMAs (no front-loaded B block,
// no forced lgkmcnt(0) -> compiler emits counted lgkmcnt, DS overlaps MFMA).

template <int BN, int MODE>
__global__ __launch_bounds__(512, 1) void gemm2(const u16* __restrict__ A, const u16* __restrict__ Bw,
                                                u16* __restrict__ Qb, u16* __restrict__ Kb,
                                                u16* __restrict__ Vb, float* __restrict__ outp,
                                                const float* __restrict__ bp) {
  constexpr int NI = BN / 32;       // per-wave ni count (wave tile 64 x BN/2)
  constexpr int NPAIR = NI / 2;     // B pairs per tile
  constexpr int NB = BN / 64;       // B gloads per wave per K-tile
  constexpr int BBYTES = BN * 128;  // one B buffer
  __shared__ __align__(16) char LDSC[65536 + 3 * BBYTES];
  const int tid = threadIdx.x, w = tid >> 6, lane = tid & 63;
  const int lr = lane & 15, lg = lane >> 4;
  // bijective XCD-chunked swizzle (grid = 32 * (N/BN), multiple of 8)
  constexpr int NBY = (BN == 192) ? 16 : 8;
  const int wg = blockIdx.x;
  const int xcd = wg & 7, loc = wg >> 3;
  const int bx = xcd * 4 + loc / NBY;
  const int by = loc % NBY;
  const int m0 = bx * 256, n0 = by * BN;
  // staging source (linear LDS dest, inverse-XOR-swizzled global chunk)
  const int r8 = lane >> 3;
  const int c8 = ((lane & 7) ^ r8) * 8;  // u16 offset
  const u16* aS[4];
  const u16* bS[3];
#pragma unroll
  for (int l = 0; l < 4; ++l) aS[l] = A + (size_t)(m0 + l * 64 + w * 8 + r8) * 1024 + c8;
#pragma unroll
  for (int l = 0; l < NB; ++l) bS[l] = Bw + (size_t)(n0 + l * 64 + w * 8 + r8) * 1024 + c8;
  const int wmB = (w >> 1) * 64, wnB = (w & 1) * (BN / 2);

  auto rdA = [&](const char* ab, int mi, int ks) -> frag8 {
    int row = wmB + mi * 16 + lr;
    return *(const frag8*)(ab + row * 128 + ((((ks << 2) + lg) ^ (lr & 7)) << 4));
  };
  auto rdB = [&](const char* bbuf, int ni, int ks) -> frag8 {
    int row = wnB + ni * 16 + lr;
    return *(const frag8*)(bbuf + row * 128 + ((((ks << 2) + lg) ^ (lr & 7)) << 4));
  };

  fx4 acc[4][NI] = {};

  // prologue: stage A(0), B(0), B(1); wait all but B(1); barrier
#pragma unroll
  for (int l = 0; l < 4; ++l) gload16(aS[l], LDSC + l * 8192 + w * 1024);
#pragma unroll
  for (int l = 0; l < NB; ++l) gload16(bS[l], LDSC + 65536 + l * 8192 + w * 1024);
#pragma unroll
  for (int l = 0; l < NB; ++l) gload16(bS[l] + 64, LDSC + 65536 + BBYTES + l * 8192 + w * 1024);
  if constexpr (NB == 3) asm volatile("s_waitcnt vmcnt(3)" ::: "memory");
  else asm volatile("s_waitcnt vmcnt(2)" ::: "memory");
  __builtin_amdgcn_s_barrier();

  for (int t = 0; t < 16; ++t) {
    const char* ab = LDSC + (t & 1) * 32768;
    const char* bb = LDSC + 65536 + (t % 3) * BBYTES;
    char* abN = LDSC + ((t + 1) & 1) * 32768;
    char* bbN = LDSC + 65536 + ((t + 2) % 3) * BBYTES;
    // issue next-tile staging first (WAR-safe: those buffers were last read
    // before the previous barrier); global ops don't block ds_reads.
    if (t + 1 < 16) {
#pragma unroll
      for (int l = 0; l < 4; ++l) gload16(aS[l] + (t + 1) * 64, abN + l * 8192 + w * 1024);
    }
    if (t + 2 < 16) {
#pragma unroll
      for (int l = 0; l < NB; ++l) gload16(bS[l] + (t + 2) * 64, bbN + l * 8192 + w * 1024);
    }
    // ---- pipelined reads: A mi=0 + B pair 0 first (6 reads), rest overlap MFMA ----
    frag8 Af[4][2];
    Af[0][0] = rdA(ab, 0, 0); Af[0][1] = rdA(ab, 0, 1);
    frag8 Bc[2][2], Bn[2][2];
    Bc[0][0] = rdB(bb, 0, 0); Bc[0][1] = rdB(bb, 0, 1);
    Bc[1][0] = rdB(bb, 1, 0); Bc[1][1] = rdB(bb, 1, 1);
#pragma unroll
    for (int p = 0; p < NPAIR; ++p) {
      if (p + 1 < NPAIR) {
        Bn[0][0] = rdB(bb, 2 * p + 2, 0); Bn[0][1] = rdB(bb, 2 * p + 2, 1);
        Bn[1][0] = rdB(bb, 2 * p + 3, 0); Bn[1][1] = rdB(bb, 2 * p + 3, 1);
      }
#pragma unroll
      for (int mi = 0; mi < 4; ++mi) {
        if (p == 0 && mi < 3) {
          Af[mi + 1][0] = rdA(ab, mi + 1, 0);
          Af[mi + 1][1] = rdA(ab, mi + 1, 1);
        }
        __builtin_amdgcn_s_setprio(1);
        acc[mi][2 * p + 0] = MFMA(Af[mi][0], Bc[0][0], acc[mi][2 * p + 0]);
        acc[mi][2 * p + 1] = MFMA(Af[mi][0], Bc[1][0], acc[mi][2 * p + 1]);
        acc[mi][2 * p + 0] = MFMA(Af[mi][1], Bc[0][1], acc[mi][2 * p + 0]);
        acc[mi][2 * p + 1] = MFMA(Af[mi][1], Bc[1][1], acc[mi][2 * p + 1]);
        __builtin_amdgcn_s_setprio(0);
      }
      if (p + 1 < NPAIR) {
        Bc[0][0] = Bn[0][0]; Bc[0][1] = Bn[0][1];
        Bc[1][0] = Bn[1][0]; Bc[1][1] = Bn[1][1];
      }
    }
    if (t < 14) {
      if constexpr (NB == 3) asm volatile("s_waitcnt vmcnt(3)" ::: "memory");
      else asm volatile("s_waitcnt vmcnt(2)" ::: "memory");
    } else {
      asm volatile("s_waitcnt vmcnt(0)" ::: "memory");
    }
    __builtin_amdgcn_s_barrier();
  }

  // epilogue
#pragma unroll
  for (int mi = 0; mi < 4; ++mi)
#pragma unroll
    for (int r = 0; r < 4; ++r) {
      int m = m0 + wmB + mi * 16 + lg * 4 + r;
      if (MODE == 0) {
        int b = m >> 11, tt = m & 2047;
#pragma unroll
        for (int ni = 0; ni < NI; ++ni) {
          int n = n0 + wnB + ni * 16 + lr;
          int type = n >> 10, h = (n >> 6) & 15, d = n & 63;
          u16* dst = (type == 0) ? Qb : ((type == 1) ? Kb : Vb);
          float v = acc[mi][ni][r];
          if (type == 0) v *= 0.04508422002778011f;  // log2(e)/32 folded into Q
          dst[((size_t)(b * 16 + h) * 2048 + tt) * 64 + d] = f2bf(v);
        }
      } else {
#pragma unroll
        for (int ni = 0; ni < NI; ++ni) {
          int n = n0 + wnB + ni * 16 + lr;
          outp[(size_t)m * 1024 + n] = acc[mi][ni][r] + bp[n];
        }
      }
    }
}

// ---------------- flash attention: 32x32 MFMA, q in lane&31, 2-phase pipeline ----------------
// grid (bh=64, 16); block = 128 q-rows, 4 waves x 32 q. KV tile 64, double-buffered.

__global__ __launch_bounds__(256, 4) void attn(const u16* __restrict__ Qb, const u16* __restrict__ Kb,
                                               const u16* __restrict__ VTg, u16* __restrict__ Ao,
                                               const int* __restrict__ mflag) {
  // LDS map (bytes): K buf0 @0, K buf1 @8192, V buf0 @16384, V buf1 @24576
  __shared__ __align__(16) char LDS[32768];
  const int tid = threadIdx.x, w = tid >> 6, lane = tid & 63;
  const int l31 = lane & 31, hi = lane >> 5;
  const int bh = blockIdx.x;
  const int qt = 15 - (int)blockIdx.y;   // big blocks first
  const int masked = mflag[0];
  const int qbase = qt * 128;
  const u16* Qh = Qb + (size_t)bh * (2048 * 64);
  const u16* Kh = Kb + (size_t)bh * (2048 * 64);
  const u16* Vh = VTg + (size_t)bh * (64 * 2048);
  const int qrow = qbase + w * 32 + l31;
  frag8 qf[4];
#pragma unroll
  for (int s = 0; s < 4; ++s) qf[s] = *(const frag8*)(Qh + (size_t)qrow * 64 + s * 16 + hi * 8);
  // staging (global_load_lds): call c covers rows c*8..c*8+7; lane chunk pre-swizzled
  const int srow = lane >> 3;
  const int schunk = ((lane & 7) ^ srow) * 8;
  const int c0 = w * 2, c1 = w * 2 + 1;
  const u16* kg0 = Kh + (size_t)(c0 * 8 + srow) * 64 + schunk;
  const u16* kg1 = Kh + (size_t)(c1 * 8 + srow) * 64 + schunk;
  const u16* vg0 = Vh + (size_t)(c0 * 8 + srow) * 2048 + schunk;
  const u16* vg1 = Vh + (size_t)(c1 * 8 + srow) * 2048 + schunk;
  // LDS read base (byte): row l31 (+slab*4096), chunk XOR swizzle
  const int aK = l31 * 128 + ((hi * 16) ^ ((l31 & 7) << 4));
  const int qmax_w = qbase + w * 32 + 31;
  const int qmin_w = qbase + w * 32;
  float m_run = -__builtin_inff(), l_run = 0.f;
  fx16 oa0 = {}, oa1 = {};
  const int nt = masked ? (2 * qt + 2) : 32;

  auto STAGE = [&](int B, int T) {
    size_t ko = (size_t)T * 4096, vo = (size_t)T * 64;
    gload16(kg0 + ko, LDS + B * 8192 + c0 * 1024);
    gload16(kg1 + ko, LDS + B * 8192 + c1 * 1024);
    gload16(vg0 + vo, LDS + 16384 + B * 8192 + c0 * 1024);
    gload16(vg1 + vo, LDS + 16384 + B * 8192 + c1 * 1024);
  };

  auto TILE = [&](auto Bc, int T) {
    constexpr int B = decltype(Bc)::value;
    if (T + 1 < nt) STAGE(B ^ 1, T + 1);
    bool act = (!masked) || (T * 64 <= qmax_w);
    if (act) {
      // ---- S^T = K * Q^T (64s x 32q) ----
      fx16 s0v = {}, s1v = {};
#pragma unroll
      for (int ds = 0; ds < 4; ++ds) {
        frag8 k0 = *(const frag8*)(LDS + B * 8192 + (aK ^ (ds << 5)));
        frag8 k1 = *(const frag8*)(LDS + B * 8192 + 4096 + (aK ^ (ds << 5)));
        s0v = MFMA32(k0, qf[ds], s0v);
        s1v = MFMA32(k1, qf[ds], s1v);
      }
      // ---- causal mask (diagonal tiles only) ----
      if (masked && T * 64 + 63 > qmin_w) {
#pragma unroll
        for (int g = 0; g < 4; ++g)
#pragma unroll
          for (int r = 0; r < 4; ++r) {
            int sg = T * 64 + r + 8 * g + 4 * hi;
            if (sg > qrow) s0v[4 * g + r] = -__builtin_inff();
            if (sg + 32 > qrow) s1v[4 * g + r] = -__builtin_inff();
          }
      }
      // ---- online softmax (row q = l31, partner = lane^32); tree reduces ----
      float tmx[8];
#pragma unroll
      for (int i = 0; i < 8; ++i)
        tmx[i] = fmaxf(fmaxf(s0v[i], s0v[i + 8]), fmaxf(s1v[i], s1v[i + 8]));
      float r0 = fmax3(tmx[0], tmx[1], tmx[2]);
      float r1 = fmax3(tmx[3], tmx[4], tmx[5]);
      float r2 = fmax3(tmx[6], tmx[7], r0);
      float mx = fmaxf(r1, r2);
      mx = fmaxf(mx, __int_as_float(__shfl_xor(__float_as_int(mx), 32)));
      if (!__all(mx <= m_run + 8.0f)) {   // defer-max (T13)
        float mn = fmaxf(m_run, mx);
        float al = __builtin_amdgcn_exp2f(m_run - mn);
#pragma unroll
        for (int i = 0; i < 16; ++i) { oa0[i] *= al; oa1[i] *= al; }
        l_run *= al;
        m_run = mn;
      }
#pragma unroll
      for (int i = 0; i < 16; ++i) s0v[i] = __builtin_amdgcn_exp2f(s0v[i] - m_run);
#pragma unroll
      for (int i = 0; i < 16; ++i) s1v[i] = __builtin_amdgcn_exp2f(s1v[i] - m_run);
      float tps[8];
#pragma unroll
      for (int i = 0; i < 8; ++i)
        tps[i] = (s0v[i] + s0v[i + 8]) + (s1v[i] + s1v[i + 8]);
      float u0 = (tps[0] + tps[1]) + (tps[2] + tps[3]);
      float u1 = (tps[4] + tps[5]) + (tps[6] + tps[7]);
      float ps = u0 + u1;
      ps += __int_as_float(__shfl_xor(__float_as_int(ps), 32));
      l_run += ps;
      // ---- O^T += V^T * P  (4 k-tiles of 16 s) ----
#pragma unroll
      for (int kt = 0; kt < 4; ++kt) {
        const int b8 = (kt & 1) * 8;
        float p0, p1, p2, p3, p4, p5, p6, p7;
        if (kt < 2) { p0=s0v[b8+0];p1=s0v[b8+1];p2=s0v[b8+2];p3=s0v[b8+3];p4=s0v[b8+4];p5=s0v[b8+5];p6=s0v[b8+6];p7=s0v[b8+7]; }
        else        { p0=s1v[b8+0];p1=s1v[b8+1];p2=s1v[b8+2];p3=s1v[b8+3];p4=s1v[b8+4];p5=s1v[b8+5];p6=s1v[b8+6];p7=s1v[b8+7]; }
        u32 X0 = cvtpk(p0, p1), X1 = cvtpk(p2, p3);
        u32 Y0 = cvtpk(p4, p5), Y1 = cvtpk(p6, p7);
        u32 sel0 = hi ? X0 : Y0, sel1 = hi ? X1 : Y1;
        u32 got0 = (u32)__shfl_xor((int)sel0, 32);
        u32 got1 = (u32)__shfl_xor((int)sel1, 32);
        union { u32 u[4]; frag8 f; } pf;
        pf.u[0] = hi ? got0 : X0;
        pf.u[1] = hi ? got1 : X1;
        pf.u[2] = hi ? Y0 : got0;
        pf.u[3] = hi ? Y1 : got1;
        frag8 v0 = *(const frag8*)(LDS + 16384 + B * 8192 + (aK ^ (kt << 5)));
        frag8 v1 = *(const frag8*)(LDS + 16384 + B * 8192 + 4096 + (aK ^ (kt << 5)));
        oa0 = MFMA32(v0, pf.f, oa0);
        oa1 = MFMA32(v1, pf.f, oa1);
      }
    }
    asm volatile("s_waitcnt vmcnt(0)" ::: "memory");
    __builtin_amdgcn_s_barrier();
  };

  STAGE(0, 0);
  asm volatile("s_waitcnt vmcnt(0)" ::: "memory");
  __builtin_amdgcn_s_barrier();
  int t = 0;
  while (true) {
    TILE(std::integral_constant<int, 0>{}, t); ++t; if (t >= nt) break;
    TILE(std::integral_constant<int, 1>{}, t); ++t; if (t >= nt) break;
  }

  // ---- epilogue: normalize + write O[q][d] ----
  float inv = 1.0f / l_run;
  int b = bh >> 4, hh = bh & 15;
  u16* orow = Ao + ((size_t)b * 2048 + qrow) * 1024 + hh * 64;
#pragma unroll
  for (int g = 0; g < 4; ++g) {
    int d0 = 8 * g + 4 * hi;
    u32 wA = cvtpk(oa0[4 * g + 0] * inv, oa0[4 * g + 1] * inv);
    u32 wB = cvtpk(oa0[4 * g + 2] * inv, oa0[4 * g + 3] * inv);
    u32 wC = cvtpk(oa1[4 * g + 0] * inv, oa1[4 * g + 1] * inv);
    u32 wD = cvtpk(oa1[4 * g + 2] * inv, oa1[4 * g + 3] * inv);
    *(u32*)(orow + d0 + 0) = wA;
    *(u32*)(orow + d0 + 2) = wB;
    *(u32*)(orow + d0 + 32) = wC;
    *(u32*)(orow + d0 + 34) = wD;
  }
}

// ---------------- launch ----------------

extern "C" void kernel_launch(void* const* d_in, const int* in_sizes, int n_in,
                              void* d_out, int out_size, void* d_ws, size_t ws_size,
                              hipStream_t stream) {
  const float* x = (const float*)d_in[0];
  const float* Wq = (const float*)d_in[1];
  const float* Wk = (const float*)d_in[2];
  const float* Wv = (const float*)d_in[3];
  const float* Wp = (const float*)d_in[4];
  const float* bp = (const float*)d_in[5];
  const int* is_masked = (const int*)d_in[6];
  float* out = (float*)d_out;
  char* ws = (char*)d_ws;
  u16* Xbf = (u16*)(ws + 0);              // 16 MB (reused as VT after gemm)
  u16* Wt  = (u16*)(ws + 16777216);       // 6 MB
  u16* Wpb = (u16*)(ws + 23068672);       // 2 MB
  u16* Qb  = (u16*)(ws + 25165824);       // 16 MB
  u16* Kb  = (u16*)(ws + 41943040);       // 16 MB
  u16* Vb  = (u16*)(ws + 58720256);       // 16 MB
  u16* Ao  = (u16*)(ws + 75497472);       // 16 MB
  u16* VTg = Xbf;                         // alias: Xbf dead after gemm

  cvt_x<<<2048, 256, 0, stream>>>(x, Xbf);
  cvt_wqkv<<<dim3(48, 16), 256, 0, stream>>>(Wq, Wk, Wv, Wt);
  cvt_wp<<<1024, 256, 0, stream>>>(Wp, Wpb);
  gemm2<192, 0><<<512, 512, 0, stream>>>(Xbf, Wt, Qb, Kb, Vb, nullptr, nullptr);
  transpose_v<<<dim3(64, 32), 256, 0, stream>>>(Vb, VTg);
  attn<<<dim3(64, 16), 256, 0, stream>>>(Qb, Kb, VTg, Ao, is_masked);
  gemm2<128, 1><<<256, 512, 0, stream>>>(Ao, Wpb, nullptr, nullptr, nullptr, out, bp);
}

// Round 13
// 159.040 us; speedup vs baseline: 1.0226x; 1.0226x over previous
//
#include <hip/hip_runtime.h>
#include <stdint.h>
#include <type_traits>

typedef unsigned short u16;
typedef unsigned int u32;
typedef __attribute__((ext_vector_type(8))) short frag8;   // 8 bf16 (4 VGPRs)
typedef __attribute__((ext_vector_type(4))) float fx4;     // 4 fp32 acc
typedef __attribute__((ext_vector_type(16))) float fx16;   // 16 fp32 acc (32x32)

#define MFMA(a, b, c) __builtin_amdgcn_mfma_f32_16x16x32_bf16((a), (b), (c), 0, 0, 0)
#define MFMA32(a, b, c) __builtin_amdgcn_mfma_f32_32x32x16_bf16((a), (b), (c), 0, 0, 0)

__device__ __forceinline__ void gload16(const void* g, void* l) {
  __builtin_amdgcn_global_load_lds((const __attribute__((address_space(1))) void*)g,
                                   (__attribute__((address_space(3))) void*)l, 16, 0, 0);
}

__device__ __forceinline__ u16 f2bf(float f) {
  union { float f; unsigned int u; } c; c.f = f;
  unsigned int r = c.u + 0x7FFFu + ((c.u >> 16) & 1u);  // RNE
  return (u16)(r >> 16);
}

__device__ __forceinline__ u32 cvtpk(float lo, float hi) {
  u32 r;
  asm("v_cvt_pk_bf16_f32 %0, %1, %2" : "=v"(r) : "v"(lo), "v"(hi));
  return r;
}

__device__ __forceinline__ float fmax3(float a, float b, float c) {
  return fmaxf(fmaxf(a, b), c);  // clang fuses to v_max3_f32
}

// ---------------- conversions ----------------

__global__ __launch_bounds__(256) void cvt_x(const float* __restrict__ x, u16* __restrict__ xb) {
  const int n4 = (8192 * 1024) / 4;
  for (int i = blockIdx.x * 256 + threadIdx.x; i < n4; i += 2048 * 256) {
    float4 v = ((const float4*)x)[i];
    ushort4 o;
    o.x = f2bf(v.x); o.y = f2bf(v.y); o.z = f2bf(v.z); o.w = f2bf(v.w);
    ((ushort4*)xb)[i] = o;
  }
}

// Wq/Wk/Wv [H][C][D] -> Wt [(h*3+type)*64+d][c]  (h-major: each BN=192 block = one head)
__global__ __launch_bounds__(256) void cvt_wqkv(const float* __restrict__ Wq,
                                                const float* __restrict__ Wk,
                                                const float* __restrict__ Wv,
                                                u16* __restrict__ Wt) {
  __shared__ u16 Tls[64][72];  // +pad
  int hh = blockIdx.x;            // 0..47
  int c0 = blockIdx.y * 64;
  int type = hh >> 4, h = hh & 15;
  const float* Wsrc = (type == 0 ? Wq : (type == 1 ? Wk : Wv)) + (size_t)h * 1024 * 64;
  int t = threadIdx.x;
  int cr = t >> 4, q4 = (t & 15) * 4;
  for (int i = 0; i < 4; ++i) {
    int c = cr + i * 16;
    float4 v = *(const float4*)(Wsrc + (size_t)(c0 + c) * 64 + q4);
    Tls[q4 + 0][c] = f2bf(v.x);
    Tls[q4 + 1][c] = f2bf(v.y);
    Tls[q4 + 2][c] = f2bf(v.z);
    Tls[q4 + 3][c] = f2bf(v.w);
  }
  __syncthreads();
  for (int i = 0; i < 4; ++i) {
    int d = cr + i * 16;
    ushort4 o;
    o.x = Tls[d][q4 + 0]; o.y = Tls[d][q4 + 1]; o.z = Tls[d][q4 + 2]; o.w = Tls[d][q4 + 3];
    *(ushort4*)(Wt + ((size_t)(h * 3 + type) * 64 + d) * 1024 + c0 + q4) = o;
  }
}

__global__ __launch_bounds__(256) void cvt_wp(const float* __restrict__ Wp, u16* __restrict__ wb) {
  const int n4 = (1024 * 1024) / 4;
  for (int i = blockIdx.x * 256 + threadIdx.x; i < n4; i += 1024 * 256) {
    float4 v = ((const float4*)Wp)[i];
    ushort4 o;
    o.x = f2bf(v.x); o.y = f2bf(v.y); o.z = f2bf(v.z); o.w = f2bf(v.w);
    ((ushort4*)wb)[i] = o;
  }
}

// ---------------- GEMM: BM=256, BN=192/128, BK=64, 512 thr (R6 loop, proven) ----------------
// MODE 0: Q/K scatter bf16 + V transposed via LDS directly to VT [bh][64][2048].
// MODE 1: +bias, fp32 out.

template <int BN, int MODE>
__global__ __launch_bounds__(512, 1) void gemm2(const u16* __restrict__ A, const u16* __restrict__ Bw,
                                                u16* __restrict__ Qb, u16* __restrict__ Kb,
                                                u16* __restrict__ VTg, float* __restrict__ outp,
                                                const float* __restrict__ bp) {
  constexpr int NI = BN / 32;       // per-wave ni count (wave tile 64 x BN/2)
  constexpr int NB = BN / 64;       // B gloads per wave per K-tile
  constexpr int BBYTES = BN * 128;  // one B buffer
  __shared__ __align__(16) char LDSC[65536 + 3 * BBYTES];
  const int tid = threadIdx.x, w = tid >> 6, lane = tid & 63;
  const int lr = lane & 15, lg = lane >> 4;
  constexpr int NBY = (BN == 192) ? 16 : 8;
  const int wg = blockIdx.x;
  const int xcd = wg & 7, loc = wg >> 3;
  const int bx = xcd * 4 + loc / NBY;
  const int by = loc % NBY;
  const int m0 = bx * 256, n0 = by * BN;
  const int r8 = lane >> 3;
  const int c8 = ((lane & 7) ^ r8) * 8;  // u16 offset
  const u16* aS[4];
  const u16* bS[3];
#pragma unroll
  for (int l = 0; l < 4; ++l) aS[l] = A + (size_t)(m0 + l * 64 + w * 8 + r8) * 1024 + c8;
#pragma unroll
  for (int l = 0; l < NB; ++l) bS[l] = Bw + (size_t)(n0 + l * 64 + w * 8 + r8) * 1024 + c8;
  const int wmB = (w >> 1) * 64, wnB = (w & 1) * (BN / 2);

  auto rdA = [&](const char* ab, int mi, int ks) -> frag8 {
    int row = wmB + mi * 16 + lr;
    return *(const frag8*)(ab + row * 128 + ((((ks << 2) + lg) ^ (lr & 7)) << 4));
  };
  auto rdB = [&](const char* bbuf, int ni, int ks) -> frag8 {
    int row = wnB + ni * 16 + lr;
    return *(const frag8*)(bbuf + row * 128 + ((((ks << 2) + lg) ^ (lr & 7)) << 4));
  };

  fx4 acc[4][NI] = {};

  // prologue: stage A(0), B(0), B(1); wait all but B(1); barrier
#pragma unroll
  for (int l = 0; l < 4; ++l) gload16(aS[l], LDSC + l * 8192 + w * 1024);
#pragma unroll
  for (int l = 0; l < NB; ++l) gload16(bS[l], LDSC + 65536 + l * 8192 + w * 1024);
#pragma unroll
  for (int l = 0; l < NB; ++l) gload16(bS[l] + 64, LDSC + 65536 + BBYTES + l * 8192 + w * 1024);
  if constexpr (NB == 3) asm volatile("s_waitcnt vmcnt(3)" ::: "memory");
  else asm volatile("s_waitcnt vmcnt(2)" ::: "memory");
  __builtin_amdgcn_s_barrier();

  for (int t = 0; t < 16; ++t) {
    const char* ab = LDSC + (t & 1) * 32768;
    const char* bb = LDSC + 65536 + (t % 3) * BBYTES;
    char* abN = LDSC + ((t + 1) & 1) * 32768;
    char* bbN = LDSC + 65536 + ((t + 2) % 3) * BBYTES;
    if (t + 1 < 16) {
#pragma unroll
      for (int l = 0; l < 4; ++l) gload16(aS[l] + (t + 1) * 64, abN + l * 8192 + w * 1024);
    }
    if (t + 2 < 16) {
#pragma unroll
      for (int l = 0; l < NB; ++l) gload16(bS[l] + (t + 2) * 64, bbN + l * 8192 + w * 1024);
    }
    frag8 Bf[NI][2];
#pragma unroll
    for (int ni = 0; ni < NI; ++ni) {
      Bf[ni][0] = rdB(bb, ni, 0);
      Bf[ni][1] = rdB(bb, ni, 1);
    }
    frag8 a0 = rdA(ab, 0, 0), a1 = rdA(ab, 0, 1);
#pragma unroll
    for (int mi = 0; mi < 4; ++mi) {
      frag8 c0 = a0, c1 = a1;
      if (mi < 3) {
        a0 = rdA(ab, mi + 1, 0);
        a1 = rdA(ab, mi + 1, 1);
      }
      __builtin_amdgcn_s_setprio(1);
#pragma unroll
      for (int ni = 0; ni < NI; ++ni) acc[mi][ni] = MFMA(c0, Bf[ni][0], acc[mi][ni]);
#pragma unroll
      for (int ni = 0; ni < NI; ++ni) acc[mi][ni] = MFMA(c1, Bf[ni][1], acc[mi][ni]);
      __builtin_amdgcn_s_setprio(0);
    }
    if (t < 14) {
      if constexpr (NB == 3) asm volatile("s_waitcnt vmcnt(3)" ::: "memory");
      else asm volatile("s_waitcnt vmcnt(2)" ::: "memory");
    } else {
      asm volatile("s_waitcnt vmcnt(0)" ::: "memory");
    }
    __builtin_amdgcn_s_barrier();
  }

  // epilogue
  if constexpr (MODE == 0) {
    const int b = m0 >> 11, t0b = m0 & 2047;
    u16* Tls = (u16*)LDSC;  // [64 d][512 B] XOR-swizzled V^T staging (32 KB)
#pragma unroll
    for (int mi = 0; mi < 4; ++mi)
#pragma unroll
      for (int r = 0; r < 4; ++r) {
        int row = wmB + mi * 16 + lg * 4 + r;  // 0..255
        int t = t0b + row;
#pragma unroll
        for (int ni = 0; ni < NI; ++ni) {
          int nl = wnB + ni * 16 + lr;  // 0..191: [0,64)=Q [64,128)=K [128,192)=V
          int type = nl >> 6, d = nl & 63;
          float v = acc[mi][ni][r];
          if (type == 0) {
            v *= 0.04508422002778011f;  // log2(e)/32 folded into Q
            Qb[((size_t)(b * 16 + by) * 2048 + t) * 64 + d] = f2bf(v);
          } else if (type == 1) {
            Kb[((size_t)(b * 16 + by) * 2048 + t) * 64 + d] = f2bf(v);
          } else {
            *(u16*)((char*)Tls + d * 512 + ((2 * row) ^ ((d & 7) << 4))) = f2bf(v);
          }
        }
      }
    __syncthreads();
    {  // coalesced V^T write: thread -> (d = tid>>3, 64B chunk c = tid&7)
      int d = tid >> 3, c = tid & 7;
      const char* src = (const char*)Tls + d * 512;
      u16* dst = VTg + ((size_t)(b * 16 + by) * 64 + d) * 2048 + t0b;
#pragma unroll
      for (int j = 0; j < 4; ++j) {
        int o = c * 64 + j * 16;
        frag8 vv = *(const frag8*)(src + (o ^ ((d & 7) << 4)));
        *(frag8*)(dst + c * 32 + j * 8) = vv;
      }
    }
  } else {
#pragma unroll
    for (int mi = 0; mi < 4; ++mi)
#pragma unroll
      for (int r = 0; r < 4; ++r) {
        int m = m0 + wmB + mi * 16 + lg * 4 + r;
#pragma unroll
        for (int ni = 0; ni < NI; ++ni) {
          int n = n0 + wnB + ni * 16 + lr;
          outp[(size_t)m * 1024 + n] = acc[mi][ni][r] + bp[n];
        }
      }
  }
}

// ---------------- flash attention: 32x32 MFMA, q in lane&31, 2-phase pipeline ----------------
// grid (bh=64, 16); block = 128 q-rows, 4 waves x 32 q. KV tile 64, double-buffered.

__global__ __launch_bounds__(256, 4) void attn(const u16* __restrict__ Qb, const u16* __restrict__ Kb,
                                               const u16* __restrict__ VTg, u16* __restrict__ Ao,
                                               const int* __restrict__ mflag) {
  // LDS map (bytes): K buf0 @0, K buf1 @8192, V buf0 @16384, V buf1 @24576
  __shared__ __align__(16) char LDS[32768];
  const int tid = threadIdx.x, w = tid >> 6, lane = tid & 63;
  const int l31 = lane & 31, hi = lane >> 5;
  const int bh = blockIdx.x;
  const int qt = 15 - (int)blockIdx.y;   // big blocks first
  const int masked = mflag[0];
  const int qbase = qt * 128;
  const u16* Qh = Qb + (size_t)bh * (2048 * 64);
  const u16* Kh = Kb + (size_t)bh * (2048 * 64);
  const u16* Vh = VTg + (size_t)bh * (64 * 2048);
  const int qrow = qbase + w * 32 + l31;
  frag8 qf[4];
#pragma unroll
  for (int s = 0; s < 4; ++s) qf[s] = *(const frag8*)(Qh + (size_t)qrow * 64 + s * 16 + hi * 8);
  const int srow = lane >> 3;
  const int schunk = ((lane & 7) ^ srow) * 8;
  const int c0 = w * 2, c1 = w * 2 + 1;
  const u16* kg0 = Kh + (size_t)(c0 * 8 + srow) * 64 + schunk;
  const u16* kg1 = Kh + (size_t)(c1 * 8 + srow) * 64 + schunk;
  const u16* vg0 = Vh + (size_t)(c0 * 8 + srow) * 2048 + schunk;
  const u16* vg1 = Vh + (size_t)(c1 * 8 + srow) * 2048 + schunk;
  const int aK = l31 * 128 + ((hi * 16) ^ ((l31 & 7) << 4));
  const int qmax_w = qbase + w * 32 + 31;
  const int qmin_w = qbase + w * 32;
  float m_run = -__builtin_inff(), l_run = 0.f;
  fx16 oa0 = {}, oa1 = {};
  const int nt = masked ? (2 * qt + 2) : 32;

  auto STAGE = [&](int B, int T) {
    size_t ko = (size_t)T * 4096, vo = (size_t)T * 64;
    gload16(kg0 + ko, LDS + B * 8192 + c0 * 1024);
    gload16(kg1 + ko, LDS + B * 8192 + c1 * 1024);
    gload16(vg0 + vo, LDS + 16384 + B * 8192 + c0 * 1024);
    gload16(vg1 + vo, LDS + 16384 + B * 8192 + c1 * 1024);
  };

  auto TILE = [&](auto Bc, int T) {
    constexpr int B = decltype(Bc)::value;
    if (T + 1 < nt) STAGE(B ^ 1, T + 1);
    bool act = (!masked) || (T * 64 <= qmax_w);
    if (act) {
      // ---- S^T = K * Q^T (64s x 32q) ----
      fx16 s0v = {}, s1v = {};
      __builtin_amdgcn_s_setprio(1);
#pragma unroll
      for (int ds = 0; ds < 4; ++ds) {
        frag8 k0 = *(const frag8*)(LDS + B * 8192 + (aK ^ (ds << 5)));
        frag8 k1 = *(const frag8*)(LDS + B * 8192 + 4096 + (aK ^ (ds << 5)));
        s0v = MFMA32(k0, qf[ds], s0v);
        s1v = MFMA32(k1, qf[ds], s1v);
      }
      __builtin_amdgcn_s_setprio(0);
      // ---- causal mask (diagonal tiles only) ----
      if (masked && T * 64 + 63 > qmin_w) {
#pragma unroll
        for (int g = 0; g < 4; ++g)
#pragma unroll
          for (int r = 0; r < 4; ++r) {
            int sg = T * 64 + r + 8 * g + 4 * hi;
            if (sg > qrow) s0v[4 * g + r] = -__builtin_inff();
            if (sg + 32 > qrow) s1v[4 * g + r] = -__builtin_inff();
          }
      }
      // ---- online softmax (row q = l31, partner = lane^32); tree reduces ----
      float tmx[8];
#pragma unroll
      for (int i = 0; i < 8; ++i)
        tmx[i] = fmaxf(fmaxf(s0v[i], s0v[i + 8]), fmaxf(s1v[i], s1v[i + 8]));
      float r0 = fmax3(tmx[0], tmx[1], tmx[2]);
      float r1 = fmax3(tmx[3], tmx[4], tmx[5]);
      float r2 = fmax3(tmx[6], tmx[7], r0);
      float mx = fmaxf(r1, r2);
      mx = fmaxf(mx, __int_as_float(__shfl_xor(__float_as_int(mx), 32)));
      if (!__all(mx <= m_run + 8.0f)) {   // defer-max (T13)
        float mn = fmaxf(m_run, mx);
        float al = __builtin_amdgcn_exp2f(m_run - mn);
#pragma unroll
        for (int i = 0; i < 16; ++i) { oa0[i] *= al; oa1[i] *= al; }
        l_run *= al;
        m_run = mn;
      }
#pragma unroll
      for (int i = 0; i < 16; ++i) s0v[i] = __builtin_amdgcn_exp2f(s0v[i] - m_run);
#pragma unroll
      for (int i = 0; i < 16; ++i) s1v[i] = __builtin_amdgcn_exp2f(s1v[i] - m_run);
      float tps[8];
#pragma unroll
      for (int i = 0; i < 8; ++i)
        tps[i] = (s0v[i] + s0v[i + 8]) + (s1v[i] + s1v[i + 8]);
      float u0 = (tps[0] + tps[1]) + (tps[2] + tps[3]);
      float u1 = (tps[4] + tps[5]) + (tps[6] + tps[7]);
      float ps = u0 + u1;
      ps += __int_as_float(__shfl_xor(__float_as_int(ps), 32));
      l_run += ps;
      // ---- O^T += V^T * P  (4 k-tiles of 16 s) ----
#pragma unroll
      for (int kt = 0; kt < 4; ++kt) {
        const int b8 = (kt & 1) * 8;
        float p0, p1, p2, p3, p4, p5, p6, p7;
        if (kt < 2) { p0=s0v[b8+0];p1=s0v[b8+1];p2=s0v[b8+2];p3=s0v[b8+3];p4=s0v[b8+4];p5=s0v[b8+5];p6=s0v[b8+6];p7=s0v[b8+7]; }
        else        { p0=s1v[b8+0];p1=s1v[b8+1];p2=s1v[b8+2];p3=s1v[b8+3];p4=s1v[b8+4];p5=s1v[b8+5];p6=s1v[b8+6];p7=s1v[b8+7]; }
        u32 X0 = cvtpk(p0, p1), X1 = cvtpk(p2, p3);
        u32 Y0 = cvtpk(p4, p5), Y1 = cvtpk(p6, p7);
        u32 sel0 = hi ? X0 : Y0, sel1 = hi ? X1 : Y1;
        u32 got0 = (u32)__shfl_xor((int)sel0, 32);
        u32 got1 = (u32)__shfl_xor((int)sel1, 32);
        union { u32 u[4]; frag8 f; } pf;
        pf.u[0] = hi ? got0 : X0;
        pf.u[1] = hi ? got1 : X1;
        pf.u[2] = hi ? Y0 : got0;
        pf.u[3] = hi ? Y1 : got1;
        frag8 v0 = *(const frag8*)(LDS + 16384 + B * 8192 + (aK ^ (kt << 5)));
        frag8 v1 = *(const frag8*)(LDS + 16384 + B * 8192 + 4096 + (aK ^ (kt << 5)));
        __builtin_amdgcn_s_setprio(1);
        oa0 = MFMA32(v0, pf.f, oa0);
        oa1 = MFMA32(v1, pf.f, oa1);
        __builtin_amdgcn_s_setprio(0);
      }
    }
    asm volatile("s_waitcnt vmcnt(0)" ::: "memory");
    __builtin_amdgcn_s_barrier();
  };

  STAGE(0, 0);
  asm volatile("s_waitcnt vmcnt(0)" ::: "memory");
  __builtin_amdgcn_s_barrier();
  int t = 0;
  while (true) {
    TILE(std::integral_constant<int, 0>{}, t); ++t; if (t >= nt) break;
    TILE(std::integral_constant<int, 1>{}, t); ++t; if (t >= nt) break;
  }

  // ---- epilogue: normalize + write O[q][d] ----
  float inv = 1.0f / l_run;
  int b = bh >> 4, hh = bh & 15;
  u16* orow = Ao + ((size_t)b * 2048 + qrow) * 1024 + hh * 64;
#pragma unroll
  for (int g = 0; g < 4; ++g) {
    int d0 = 8 * g + 4 * hi;
    u32 wA = cvtpk(oa0[4 * g + 0] * inv, oa0[4 * g + 1] * inv);
    u32 wB = cvtpk(oa0[4 * g + 2] * inv, oa0[4 * g + 3] * inv);
    u32 wC = cvtpk(oa1[4 * g + 0] * inv, oa1[4 * g + 1] * inv);
    u32 wD = cvtpk(oa1[4 * g + 2] * inv, oa1[4 * g + 3] * inv);
    *(u32*)(orow + d0 + 0) = wA;
    *(u32*)(orow + d0 + 2) = wB;
    *(u32*)(orow + d0 + 32) = wC;
    *(u32*)(orow + d0 + 34) = wD;
  }
}

// ---------------- launch ----------------

extern "C" void kernel_launch(void* const* d_in, const int* in_sizes, int n_in,
                              void* d_out, int out_size, void* d_ws, size_t ws_size,
                              hipStream_t stream) {
  const float* x = (const float*)d_in[0];
  const float* Wq = (const float*)d_in[1];
  const float* Wk = (const float*)d_in[2];
  const float* Wv = (const float*)d_in[3];
  const float* Wp = (const float*)d_in[4];
  const float* bp = (const float*)d_in[5];
  const int* is_masked = (const int*)d_in[6];
  float* out = (float*)d_out;
  char* ws = (char*)d_ws;
  u16* Xbf = (u16*)(ws + 0);              // 16 MB
  u16* Wt  = (u16*)(ws + 16777216);       // 6 MB
  u16* Wpb = (u16*)(ws + 23068672);       // 2 MB
  u16* Qb  = (u16*)(ws + 25165824);       // 16 MB
  u16* Kb  = (u16*)(ws + 41943040);       // 16 MB
  u16* VT  = (u16*)(ws + 58720256);       // 16 MB (V^T written directly by gemm)
  u16* Ao  = (u16*)(ws + 75497472);       // 16 MB

  cvt_x<<<2048, 256, 0, stream>>>(x, Xbf);
  cvt_wqkv<<<dim3(48, 16), 256, 0, stream>>>(Wq, Wk, Wv, Wt);
  cvt_wp<<<1024, 256, 0, stream>>>(Wp, Wpb);
  gemm2<192, 0><<<512, 512, 0, stream>>>(Xbf, Wt, Qb, Kb, VT, nullptr, nullptr);
  attn<<<dim3(64, 16), 256, 0, stream>>>(Qb, Kb, VT, Ao, is_masked);
  gemm2<128, 1><<<256, 512, 0, stream>>>(Ao, Wpb, nullptr, nullptr, nullptr, out, bp);
}